// Round 1
// baseline (1109.040 us; speedup 1.0000x reference)
//
#include <hip/hip_runtime.h>
#include <hip/hip_bf16.h>

// ---------------------------------------------------------------------------
// Fused pipeline (R10): conv producer + GRU consumer OVERLAPPED in ONE kernel.
//   Blocks 0..63          : GRU (16 batches each), spin-waits per enc step on
//                           per-timestep completion counters (agent scope).
//   Blocks 64..7743       : conv, 4 images per 256-thr block (4x64 subgroups),
//                           image order is TIMESTEP-MAJOR so ctr[t] completes
//                           in order. Publish: agent-scope stores + release add.
// Dependency is now per-timestep, not per-kernel: encoder hides under conv,
// exposed tail = decoder only. Worst-case (adverse dispatch order) = old
// serial schedule; correctness never depends on scheduling (G16).
// ---------------------------------------------------------------------------

#define B_      1024
#define L_      30
#define H_      64
#define NGRUBLK 64

typedef _Float16 half_t;
typedef __attribute__((ext_vector_type(8))) _Float16 half8;
typedef __attribute__((ext_vector_type(4))) float f32x4;

#define MFMA16(A, B, C) __builtin_amdgcn_mfma_f32_16x16x32_f16(A, B, C, 0, 0, 0)

__device__ __forceinline__ float sigmoid_f(float v) {
    return __builtin_amdgcn_rcpf(1.f + __expf(-v));
}
__device__ __forceinline__ float tanh_f(float v) {
    v = fminf(fmaxf(v, -15.f), 15.f);
    const float e = __expf(2.f * v);
    return (e - 1.f) * __builtin_amdgcn_rcpf(e + 1.f);
}
__device__ __forceinline__ void load4_lds(float* r, const float* p) {
    float2 a = *(const float2*)p;
    float2 b = *(const float2*)(p + 2);
    r[0] = a.x; r[1] = a.y; r[2] = b.x; r[3] = b.y;
}

// LDS union: conv role needs 4x9616B = 38464B; GRU role needs 7168B.
union alignas(16) SharedU {
    struct {
        half_t hbuf[2][16][72];   // [parity][batch][unit], rows padded 64->72
        half_t xenc[16][40];      // current-step x, cols 0..8 live, rest zero
        half_t xdec[16][40];      // decoder x,    cols 0..3 live, rest zero
    } g;
    struct {
        float s_img[32 * 32];
        float s_p1[4 * 15 * 16];  // [c][py][px], width padded to 16
        float s_p2[360];
        float s_red[60];
    } c[4];
};

__global__ __launch_bounds__(256, 3) void fused_kernel(
    const float* __restrict__ bbox,
    const float* __restrict__ head,
    const float* __restrict__ c1w, const float* __restrict__ c1b,
    const float* __restrict__ c2w, const float* __restrict__ c2b,
    const float* __restrict__ fcw, const float* __restrict__ fcb,
    const float* __restrict__ ewih, const float* __restrict__ ewhh,
    const float* __restrict__ ebih, const float* __restrict__ ebhh,
    const float* __restrict__ dwih, const float* __restrict__ dwhh,
    const float* __restrict__ dbih, const float* __restrict__ dbhh,
    const float* __restrict__ linw, const float* __restrict__ linb,
    float* __restrict__ enc_in,     // [1024][30][9] in d_ws
    unsigned*            ctr,       // [30] in d_ws, pre-zeroed via memset
    float* __restrict__ out)        // [1024][20][4]
{
    __shared__ SharedU su;
    const int tid = threadIdx.x;

    if (blockIdx.x >= NGRUBLK) {
        // ===================== conv role (4 images / block) =================
        const int sub  = tid >> 6;
        const int lane = tid & 63;
        const int img  = (((int)blockIdx.x - NGRUBLK) << 2) | sub;
        const int ts   = img >> 10;       // timestep-major ordering
        const int b    = img & 1023;
        auto& S = su.c[sub];

        {
            const float4* src = (const float4*)(head + ((size_t)b * 31 + (size_t)ts) * 1024);
            float4* dstv = (float4*)S.s_img;
            #pragma unroll
            for (int i = 0; i < 4; ++i) dstv[lane + 64 * i] = src[lane + 64 * i];
        }
        __syncthreads();

        if (lane < 60) {
            const int c = lane / 15, px = lane % 15;
            const int x0 = 2 * px;
            float wg[9];
            #pragma unroll
            for (int k = 0; k < 9; ++k) wg[k] = c1w[c * 9 + k];
            const float bias = c1b[c];

            auto c1out = [&](const float* ra, const float* rb, const float* rc, const float* rd) -> float {
                float a00 = bias, a01 = bias, a10 = bias, a11 = bias;
                #pragma unroll
                for (int kx = 0; kx < 3; ++kx) {
                    const float w0 = wg[kx], w1 = wg[3 + kx], w2 = wg[6 + kx];
                    a00 = fmaf(w0, ra[kx],     fmaf(w1, rb[kx],     fmaf(w2, rc[kx],     a00)));
                    a01 = fmaf(w0, ra[kx + 1], fmaf(w1, rb[kx + 1], fmaf(w2, rc[kx + 1], a01)));
                    a10 = fmaf(w0, rb[kx],     fmaf(w1, rc[kx],     fmaf(w2, rd[kx],     a10)));
                    a11 = fmaf(w0, rb[kx + 1], fmaf(w1, rc[kx + 1], fmaf(w2, rd[kx + 1], a11)));
                }
                a00 = fmaxf(a00, 0.f); a01 = fmaxf(a01, 0.f);
                a10 = fmaxf(a10, 0.f); a11 = fmaxf(a11, 0.f);
                return fmaxf(fmaxf(a00, a01), fmaxf(a10, a11));
            };

            float r[6][4];
            load4_lds(r[0], S.s_img + 0 * 32 + x0);
            load4_lds(r[1], S.s_img + 1 * 32 + x0);
            #pragma unroll
            for (int i = 0; i < 7; ++i) {
                const int s0 = (4 * i) % 6, s1 = (4 * i + 1) % 6, s2 = (4 * i + 2) % 6;
                const int s3 = (4 * i + 3) % 6, s4 = (4 * i + 4) % 6, s5 = (4 * i + 5) % 6;
                load4_lds(r[s2], S.s_img + (4 * i + 2) * 32 + x0);
                load4_lds(r[s3], S.s_img + (4 * i + 3) * 32 + x0);
                S.s_p1[c * 240 + (2 * i) * 16 + px] = c1out(r[s0], r[s1], r[s2], r[s3]);
                load4_lds(r[s4], S.s_img + (4 * i + 4) * 32 + x0);
                load4_lds(r[s5], S.s_img + (4 * i + 5) * 32 + x0);
                S.s_p1[c * 240 + (2 * i + 1) * 16 + px] = c1out(r[s2], r[s3], r[s4], r[s5]);
            }
            load4_lds(r[0], S.s_img + 30 * 32 + x0);
            load4_lds(r[1], S.s_img + 31 * 32 + x0);
            S.s_p1[c * 240 + 14 * 16 + px] = c1out(r[4], r[5], r[0], r[1]);
        }
        __syncthreads();

        if (lane < 60) {
            const int c = lane / 6, px = lane % 6;
            const int x0 = 2 * px;
            float wg2[4][9];
            #pragma unroll
            for (int ic = 0; ic < 4; ++ic)
                #pragma unroll
                for (int k = 0; k < 9; ++k) wg2[ic][k] = c2w[(c * 4 + ic) * 9 + k];
            const float bias2 = c2b[c];

            float P[6][4][4];
            auto c2out = [&](float (*pa)[4], float (*pb)[4], float (*pc)[4], float (*pd)[4]) -> float {
                float a00 = bias2, a01 = bias2, a10 = bias2, a11 = bias2;
                #pragma unroll
                for (int ic = 0; ic < 4; ++ic) {
                    #pragma unroll
                    for (int kx = 0; kx < 3; ++kx) {
                        const float w0 = wg2[ic][kx], w1 = wg2[ic][3 + kx], w2 = wg2[ic][6 + kx];
                        a00 = fmaf(w0, pa[ic][kx],     fmaf(w1, pb[ic][kx],     fmaf(w2, pc[ic][kx],     a00)));
                        a01 = fmaf(w0, pa[ic][kx + 1], fmaf(w1, pb[ic][kx + 1], fmaf(w2, pc[ic][kx + 1], a01)));
                        a10 = fmaf(w0, pb[ic][kx],     fmaf(w1, pc[ic][kx],     fmaf(w2, pd[ic][kx],     a10)));
                        a11 = fmaf(w0, pb[ic][kx + 1], fmaf(w1, pc[ic][kx + 1], fmaf(w2, pd[ic][kx + 1], a11)));
                    }
                }
                a00 = fmaxf(a00, 0.f); a01 = fmaxf(a01, 0.f);
                a10 = fmaxf(a10, 0.f); a11 = fmaxf(a11, 0.f);
                return fmaxf(fmaxf(a00, a01), fmaxf(a10, a11));
            };

            #pragma unroll
            for (int ic = 0; ic < 4; ++ic) {
                load4_lds(P[0][ic], S.s_p1 + ic * 240 + 0 * 16 + x0);
                load4_lds(P[1][ic], S.s_p1 + ic * 240 + 1 * 16 + x0);
            }
            #pragma unroll
            for (int i = 0; i < 3; ++i) {
                const int s0 = (4 * i) % 6, s1 = (4 * i + 1) % 6, s2 = (4 * i + 2) % 6;
                const int s3 = (4 * i + 3) % 6, s4 = (4 * i + 4) % 6, s5 = (4 * i + 5) % 6;
                #pragma unroll
                for (int ic = 0; ic < 4; ++ic) {
                    load4_lds(P[s2][ic], S.s_p1 + ic * 240 + (4 * i + 2) * 16 + x0);
                    load4_lds(P[s3][ic], S.s_p1 + ic * 240 + (4 * i + 3) * 16 + x0);
                }
                S.s_p2[c * 36 + (2 * i) * 6 + px] = c2out(P[s0], P[s1], P[s2], P[s3]);
                #pragma unroll
                for (int ic = 0; ic < 4; ++ic) {
                    load4_lds(P[s4][ic], S.s_p1 + ic * 240 + (4 * i + 4) * 16 + x0);
                    load4_lds(P[s5][ic], S.s_p1 + ic * 240 + (4 * i + 5) * 16 + x0);
                }
                S.s_p2[c * 36 + (2 * i + 1) * 6 + px] = c2out(P[s2], P[s3], P[s4], P[s5]);
            }
        }
        __syncthreads();

        if (lane < 60) {
            const int o = lane / 12, i0 = lane % 12;
            const float* wrow = fcw + o * 360;
            float acc = 0.f;
            #pragma unroll
            for (int k = 0; k < 30; ++k) {
                const int i = i0 + 12 * k;
                acc = fmaf(wrow[i], S.s_p2[i], acc);
            }
            S.s_red[lane] = acc;
        }
        __syncthreads();

        // publish: agent-scope stores so the GRU blocks (other XCDs, no
        // dispatch-boundary cache flush anymore) read coherent data.
        float* dst = enc_in + ((size_t)b * L_ + ts) * 9;
        if (lane < 5) {
            float acc = fcb[lane];
            #pragma unroll
            for (int k = 0; k < 12; ++k) acc += S.s_red[lane * 12 + k];
            __hip_atomic_store(&dst[4 + lane], acc, __ATOMIC_RELAXED, __HIP_MEMORY_SCOPE_AGENT);
        } else if (lane >= 8 && lane < 12) {
            const int d = lane - 8;
            const float* bbp = bbox + (size_t)b * 124 + (size_t)ts * 4;
            __hip_atomic_store(&dst[d], bbp[4 + d] - bbp[d], __ATOMIC_RELAXED, __HIP_MEMORY_SCOPE_AGENT);
        }
        __syncthreads();   // drains vmcnt -> all 4 sub-images' stores complete
        if (lane == 0)
            __hip_atomic_fetch_add(&ctr[ts], 1u, __ATOMIC_RELEASE, __HIP_MEMORY_SCOPE_AGENT);
        return;
    }

    // ======================= GRU role (blocks 0..63) ========================
    const int bb  = (int)blockIdx.x * 16;   // first batch of this block
    const int w   = tid >> 6;               // wave 0..3
    const int l   = tid & 63;
    const int q   = l >> 4;                 // quad 0..3
    const int col = l & 15;
    auto& G = su.g;

    // ---- zero LDS (7168 B = 448 int4) --------------------------------------
    {
        int4* p = (int4*)&G;
        #pragma unroll
        for (int i = 0; i < 2; ++i) {
            const int idx = tid + 256 * i;
            if (idx < (int)(sizeof(G) / 16)) p[idx] = int4{0, 0, 0, 0};
        }
    }

    // ---- weight B-fragments (register-resident, f16) -----------------------
    const int urow = 16 * w + col;
    auto whh_frag = [&](const float* W, int gate, int kap) -> half8 {
        const float* rp = W + (size_t)(gate * 64 + urow) * 64 + kap * 32 + q * 8;
        half8 f;
        #pragma unroll
        for (int j = 0; j < 8; ++j) f[j] = (half_t)rp[j];
        return f;
    };
    auto wih_frag = [&](const float* W, int gate, int indim) -> half8 {
        half8 f;
        #pragma unroll
        for (int j = 0; j < 8; ++j) {
            const int d = q * 8 + j;
            f[j] = (d < indim) ? (half_t)W[(size_t)(gate * 64 + urow) * indim + d]
                               : (half_t)0.f;
        }
        return f;
    };

    // encoder frags only (decoder frags loaded after the encoder loop to keep
    // peak VGPR under the __launch_bounds__(256,3) cap)
    const half8 eBr0 = whh_frag(ewhh, 0, 0), eBr1 = whh_frag(ewhh, 0, 1);
    const half8 eBz0 = whh_frag(ewhh, 1, 0), eBz1 = whh_frag(ewhh, 1, 1);
    const half8 eBn0 = whh_frag(ewhh, 2, 0), eBn1 = whh_frag(ewhh, 2, 1);
    const half8 eBrx = wih_frag(ewih, 0, 9);
    const half8 eBzx = wih_frag(ewih, 1, 9);
    const half8 eBnx = wih_frag(ewih, 2, 9);

    const float ebr  = ebih[urow]       + ebhh[urow];
    const float ebz  = ebih[64 + urow]  + ebhh[64 + urow];
    const float ebnh = ebhh[128 + urow];
    const float ebni = ebih[128 + urow];

    float hold[4] = {0.f, 0.f, 0.f, 0.f};
    __syncthreads();   // LDS zeros visible

    // =================== encoder: 30 steps, paced by conv ==================
    for (int t = 0; t < L_; ++t) {
        if (tid == 0) {
            while (__hip_atomic_load(&ctr[t], __ATOMIC_ACQUIRE, __HIP_MEMORY_SCOPE_AGENT)
                   < (unsigned)B_)
                __builtin_amdgcn_s_sleep(2);
        }
        __syncthreads();
        if (tid < 144) {   // stage 16 batches x 9 dims for this step
            const int bq = tid / 9, d = tid - 9 * bq;
            const float v = __hip_atomic_load(
                &enc_in[((size_t)(bb + bq) * L_ + t) * 9 + d],
                __ATOMIC_RELAXED, __HIP_MEMORY_SCOPE_AGENT);
            G.xenc[bq][d] = (half_t)v;
        }
        __syncthreads();

        const int p = t & 1;
        const half8 a0 = *(const half8*)&G.hbuf[p][col][q * 8];        // k 0..31
        const half8 a1 = *(const half8*)&G.hbuf[p][col][32 + q * 8];   // k 32..63
        const half8 a2 = *(const half8*)&G.xenc[col][q * 8];           // k 64..95

        f32x4 Cr  = {ebr, ebr, ebr, ebr};
        f32x4 Cz  = {ebz, ebz, ebz, ebz};
        f32x4 Cnh = {ebnh, ebnh, ebnh, ebnh};
        f32x4 Cnx = {ebni, ebni, ebni, ebni};
        Cr  = MFMA16(a0, eBr0, Cr);  Cr  = MFMA16(a1, eBr1, Cr);  Cr = MFMA16(a2, eBrx, Cr);
        Cz  = MFMA16(a0, eBz0, Cz);  Cz  = MFMA16(a1, eBz1, Cz);  Cz = MFMA16(a2, eBzx, Cz);
        Cnh = MFMA16(a0, eBn0, Cnh); Cnh = MFMA16(a1, eBn1, Cnh);
        Cnx = MFMA16(a2, eBnx, Cnx);

        #pragma unroll
        for (int r = 0; r < 4; ++r) {
            const float rr = sigmoid_f(Cr[r]);
            const float zz = sigmoid_f(Cz[r]);
            const float nn = tanh_f(Cnx[r] + rr * Cnh[r]);
            hold[r] = fmaf(zz, hold[r] - nn, nn);
            G.hbuf[p ^ 1][q * 4 + r][urow] = (half_t)hold[r];
        }
        __syncthreads();
    }

    // ---- decoder weights / lin head / x0 (loaded after encoder) ------------
    const half8 dBr0 = whh_frag(dwhh, 0, 0), dBr1 = whh_frag(dwhh, 0, 1);
    const half8 dBz0 = whh_frag(dwhh, 1, 0), dBz1 = whh_frag(dwhh, 1, 1);
    const half8 dBn0 = whh_frag(dwhh, 2, 0), dBn1 = whh_frag(dwhh, 2, 1);
    const half8 dBrx = wih_frag(dwih, 0, 4);
    const half8 dBzx = wih_frag(dwih, 1, 4);
    const half8 dBnx = wih_frag(dwih, 2, 4);

    half8 Bl0, Bl1;
    #pragma unroll
    for (int j = 0; j < 8; ++j) {
        Bl0[j] = (col < 4) ? (half_t)linw[col * 64 +      q * 8 + j] : (half_t)0.f;
        Bl1[j] = (col < 4) ? (half_t)linw[col * 64 + 32 + q * 8 + j] : (half_t)0.f;
    }

    const float dbr  = dbih[urow]       + dbhh[urow];
    const float dbz  = dbih[64 + urow]  + dbhh[64 + urow];
    const float dbnh = dbhh[128 + urow];
    const float dbni = dbih[128 + urow];
    const float lb   = (col < 4) ? linb[col] : 0.f;

    float xold[4], ofs[4], cs[4];
    if (w == 0 && col < 4) {
        #pragma unroll
        for (int r = 0; r < 4; ++r) {
            const float* bbp = bbox + (size_t)(bb + q * 4 + r) * 124;
            xold[r] = bbp[120 + col] - bbp[116 + col];
            ofs[r]  = bbp[120 + col];
            cs[r]   = 0.f;
            G.xdec[q * 4 + r][col] = (half_t)xold[r];
        }
    }
    __syncthreads();   // xdec visible

    // =================== decoder: 20 steps + lin + cumsum ==================
    for (int tt = 0; tt < 20; ++tt) {
        const int p = tt & 1;   // (30+tt)&1 == tt&1
        const half8 a0 = *(const half8*)&G.hbuf[p][col][q * 8];
        const half8 a1 = *(const half8*)&G.hbuf[p][col][32 + q * 8];
        const half8 a2 = *(const half8*)&G.xdec[col][q * 8];

        f32x4 Cr  = {dbr, dbr, dbr, dbr};
        f32x4 Cz  = {dbz, dbz, dbz, dbz};
        f32x4 Cnh = {dbnh, dbnh, dbnh, dbnh};
        f32x4 Cnx = {dbni, dbni, dbni, dbni};
        Cr  = MFMA16(a0, dBr0, Cr);  Cr  = MFMA16(a1, dBr1, Cr);  Cr = MFMA16(a2, dBrx, Cr);
        Cz  = MFMA16(a0, dBz0, Cz);  Cz  = MFMA16(a1, dBz1, Cz);  Cz = MFMA16(a2, dBzx, Cz);
        Cnh = MFMA16(a0, dBn0, Cnh); Cnh = MFMA16(a1, dBn1, Cnh);
        Cnx = MFMA16(a2, dBnx, Cnx);

        #pragma unroll
        for (int r = 0; r < 4; ++r) {
            const float rr = sigmoid_f(Cr[r]);
            const float zz = sigmoid_f(Cz[r]);
            const float nn = tanh_f(Cnx[r] + rr * Cnh[r]);
            hold[r] = fmaf(zz, hold[r] - nn, nn);
            G.hbuf[p ^ 1][q * 4 + r][urow] = (half_t)hold[r];
        }
        __syncthreads();   // (A) h_new visible for lin-head A-frags

        const half8 al0 = *(const half8*)&G.hbuf[p ^ 1][col][q * 8];
        const half8 al1 = *(const half8*)&G.hbuf[p ^ 1][col][32 + q * 8];
        f32x4 X = {0.f, 0.f, 0.f, 0.f};
        X = MFMA16(al0, Bl0, X);
        X = MFMA16(al1, Bl1, X);

        if (w == 0 && col < 4) {
            #pragma unroll
            for (int r = 0; r < 4; ++r) {
                const float xv = X[r] + lb + xold[r];
                xold[r] = xv;
                cs[r] += xv;
                G.xdec[q * 4 + r][col] = (half_t)xv;
                out[(size_t)(bb + q * 4 + r) * 80 + tt * 4 + col] = cs[r] + ofs[r];
            }
        }
        __syncthreads();   // (B) xdec visible for next step's gi
    }
}

// ---------------------------------------------------------------------------
extern "C" void kernel_launch(void* const* d_in, const int* in_sizes, int n_in,
                              void* d_out, int out_size, void* d_ws, size_t ws_size,
                              hipStream_t stream) {
    (void)in_sizes; (void)n_in; (void)out_size; (void)ws_size;
    const float* bbox = (const float*)d_in[0];
    const float* head = (const float*)d_in[1];
    const float* c1w  = (const float*)d_in[2];
    const float* c1b  = (const float*)d_in[3];
    const float* c2w  = (const float*)d_in[4];
    const float* c2b  = (const float*)d_in[5];
    const float* fcw  = (const float*)d_in[6];
    const float* fcb  = (const float*)d_in[7];
    const float* ewih = (const float*)d_in[8];
    const float* ewhh = (const float*)d_in[9];
    const float* ebih = (const float*)d_in[10];
    const float* ebhh = (const float*)d_in[11];
    const float* dwih = (const float*)d_in[12];
    const float* dwhh = (const float*)d_in[13];
    const float* dbih = (const float*)d_in[14];
    const float* dbhh = (const float*)d_in[15];
    const float* linw = (const float*)d_in[16];
    const float* linb = (const float*)d_in[17];
    float* out = (float*)d_out;

    float*    enc_in = (float*)d_ws;                       // 1024*30*9 floats
    unsigned* ctr    = (unsigned*)((char*)d_ws + (size_t)B_ * L_ * 9 * sizeof(float));

    hipMemsetAsync(ctr, 0, 32 * sizeof(unsigned), stream); // graph-capturable

    const int grid = NGRUBLK + (B_ * L_) / 4;              // 64 gru + 7680 conv
    fused_kernel<<<grid, 256, 0, stream>>>(bbox, head, c1w, c1b, c2w, c2b,
                                           fcw, fcb, ewih, ewhh, ebih, ebhh,
                                           dwih, dwhh, dbih, dbhh, linw, linb,
                                           enc_in, ctr, out);
}

// Round 2
// 703.858 us; speedup vs baseline: 1.5757x; 1.5757x over previous
//
#include <hip/hip_runtime.h>
#include <hip/hip_bf16.h>

// ---------------------------------------------------------------------------
// Fused pipeline (R11): conv producer + GRU consumer OVERLAPPED in ONE kernel.
//   R10 post-mortem: agent-scope ACQUIRE (spin poll) / RELEASE (per-block add)
//   compile to buffer_inv / buffer_wbl2 on gfx950 (per-XCD L2 non-coherent).
//   Issued continuously they keep every XCD's TCC in perpetual drain -> conv
//   loads see multi-us latency -> VALUBusy 101%->9%, dur x10.
//   Fix: RELAXED everywhere. All communicated data (enc_in, ctr) is accessed
//   via agent-scope atomics on BOTH sides (cache-bypassing, performed at the
//   coherent point), so ordering needs only:
//     producer: __syncthreads() drains vmcnt (stores COMPLETE at coherent
//               point) before the relaxed fetch_add issues.
//     consumer: control dependency (poll==1024) before staging loads issue;
//               bypassing loads cannot hit stale cache.
//   No buffer_inv / buffer_wbl2 in the hot path at all.
// ---------------------------------------------------------------------------

#define B_      1024
#define L_      30
#define H_      64
#define NGRUBLK 64

typedef _Float16 half_t;
typedef __attribute__((ext_vector_type(8))) _Float16 half8;
typedef __attribute__((ext_vector_type(4))) float f32x4;

#define MFMA16(A, B, C) __builtin_amdgcn_mfma_f32_16x16x32_f16(A, B, C, 0, 0, 0)

__device__ __forceinline__ float sigmoid_f(float v) {
    return __builtin_amdgcn_rcpf(1.f + __expf(-v));
}
__device__ __forceinline__ float tanh_f(float v) {
    v = fminf(fmaxf(v, -15.f), 15.f);
    const float e = __expf(2.f * v);
    return (e - 1.f) * __builtin_amdgcn_rcpf(e + 1.f);
}
__device__ __forceinline__ void load4_lds(float* r, const float* p) {
    float2 a = *(const float2*)p;
    float2 b = *(const float2*)(p + 2);
    r[0] = a.x; r[1] = a.y; r[2] = b.x; r[3] = b.y;
}

// LDS union: conv role needs 4x9616B = 38464B; GRU role needs 7168B.
union alignas(16) SharedU {
    struct {
        half_t hbuf[2][16][72];   // [parity][batch][unit], rows padded 64->72
        half_t xenc[16][40];      // current-step x, cols 0..8 live, rest zero
        half_t xdec[16][40];      // decoder x,    cols 0..3 live, rest zero
    } g;
    struct {
        float s_img[32 * 32];
        float s_p1[4 * 15 * 16];  // [c][py][px], width padded to 16
        float s_p2[360];
        float s_red[60];
    } c[4];
};

__global__ __launch_bounds__(256, 3) void fused_kernel(
    const float* __restrict__ bbox,
    const float* __restrict__ head,
    const float* __restrict__ c1w, const float* __restrict__ c1b,
    const float* __restrict__ c2w, const float* __restrict__ c2b,
    const float* __restrict__ fcw, const float* __restrict__ fcb,
    const float* __restrict__ ewih, const float* __restrict__ ewhh,
    const float* __restrict__ ebih, const float* __restrict__ ebhh,
    const float* __restrict__ dwih, const float* __restrict__ dwhh,
    const float* __restrict__ dbih, const float* __restrict__ dbhh,
    const float* __restrict__ linw, const float* __restrict__ linb,
    float* __restrict__ enc_in,     // [1024][30][9] in d_ws
    unsigned*            ctr,       // [30] in d_ws, pre-zeroed via memset
    float* __restrict__ out)        // [1024][20][4]
{
    __shared__ SharedU su;
    const int tid = threadIdx.x;

    if (blockIdx.x >= NGRUBLK) {
        // ===================== conv role (4 images / block) =================
        const int sub  = tid >> 6;
        const int lane = tid & 63;
        const int img  = (((int)blockIdx.x - NGRUBLK) << 2) | sub;
        const int ts   = img >> 10;       // timestep-major ordering
        const int b    = img & 1023;
        auto& S = su.c[sub];

        {
            const float4* src = (const float4*)(head + ((size_t)b * 31 + (size_t)ts) * 1024);
            float4* dstv = (float4*)S.s_img;
            #pragma unroll
            for (int i = 0; i < 4; ++i) dstv[lane + 64 * i] = src[lane + 64 * i];
        }
        __syncthreads();

        if (lane < 60) {
            const int c = lane / 15, px = lane % 15;
            const int x0 = 2 * px;
            float wg[9];
            #pragma unroll
            for (int k = 0; k < 9; ++k) wg[k] = c1w[c * 9 + k];
            const float bias = c1b[c];

            auto c1out = [&](const float* ra, const float* rb, const float* rc, const float* rd) -> float {
                float a00 = bias, a01 = bias, a10 = bias, a11 = bias;
                #pragma unroll
                for (int kx = 0; kx < 3; ++kx) {
                    const float w0 = wg[kx], w1 = wg[3 + kx], w2 = wg[6 + kx];
                    a00 = fmaf(w0, ra[kx],     fmaf(w1, rb[kx],     fmaf(w2, rc[kx],     a00)));
                    a01 = fmaf(w0, ra[kx + 1], fmaf(w1, rb[kx + 1], fmaf(w2, rc[kx + 1], a01)));
                    a10 = fmaf(w0, rb[kx],     fmaf(w1, rc[kx],     fmaf(w2, rd[kx],     a10)));
                    a11 = fmaf(w0, rb[kx + 1], fmaf(w1, rc[kx + 1], fmaf(w2, rd[kx + 1], a11)));
                }
                a00 = fmaxf(a00, 0.f); a01 = fmaxf(a01, 0.f);
                a10 = fmaxf(a10, 0.f); a11 = fmaxf(a11, 0.f);
                return fmaxf(fmaxf(a00, a01), fmaxf(a10, a11));
            };

            float r[6][4];
            load4_lds(r[0], S.s_img + 0 * 32 + x0);
            load4_lds(r[1], S.s_img + 1 * 32 + x0);
            #pragma unroll
            for (int i = 0; i < 7; ++i) {
                const int s0 = (4 * i) % 6, s1 = (4 * i + 1) % 6, s2 = (4 * i + 2) % 6;
                const int s3 = (4 * i + 3) % 6, s4 = (4 * i + 4) % 6, s5 = (4 * i + 5) % 6;
                load4_lds(r[s2], S.s_img + (4 * i + 2) * 32 + x0);
                load4_lds(r[s3], S.s_img + (4 * i + 3) * 32 + x0);
                S.s_p1[c * 240 + (2 * i) * 16 + px] = c1out(r[s0], r[s1], r[s2], r[s3]);
                load4_lds(r[s4], S.s_img + (4 * i + 4) * 32 + x0);
                load4_lds(r[s5], S.s_img + (4 * i + 5) * 32 + x0);
                S.s_p1[c * 240 + (2 * i + 1) * 16 + px] = c1out(r[s2], r[s3], r[s4], r[s5]);
            }
            load4_lds(r[0], S.s_img + 30 * 32 + x0);
            load4_lds(r[1], S.s_img + 31 * 32 + x0);
            S.s_p1[c * 240 + 14 * 16 + px] = c1out(r[4], r[5], r[0], r[1]);
        }
        __syncthreads();

        if (lane < 60) {
            const int c = lane / 6, px = lane % 6;
            const int x0 = 2 * px;
            float wg2[4][9];
            #pragma unroll
            for (int ic = 0; ic < 4; ++ic)
                #pragma unroll
                for (int k = 0; k < 9; ++k) wg2[ic][k] = c2w[(c * 4 + ic) * 9 + k];
            const float bias2 = c2b[c];

            float P[6][4][4];
            auto c2out = [&](float (*pa)[4], float (*pb)[4], float (*pc)[4], float (*pd)[4]) -> float {
                float a00 = bias2, a01 = bias2, a10 = bias2, a11 = bias2;
                #pragma unroll
                for (int ic = 0; ic < 4; ++ic) {
                    #pragma unroll
                    for (int kx = 0; kx < 3; ++kx) {
                        const float w0 = wg2[ic][kx], w1 = wg2[ic][3 + kx], w2 = wg2[ic][6 + kx];
                        a00 = fmaf(w0, pa[ic][kx],     fmaf(w1, pb[ic][kx],     fmaf(w2, pc[ic][kx],     a00)));
                        a01 = fmaf(w0, pa[ic][kx + 1], fmaf(w1, pb[ic][kx + 1], fmaf(w2, pc[ic][kx + 1], a01)));
                        a10 = fmaf(w0, pb[ic][kx],     fmaf(w1, pc[ic][kx],     fmaf(w2, pd[ic][kx],     a10)));
                        a11 = fmaf(w0, pb[ic][kx + 1], fmaf(w1, pc[ic][kx + 1], fmaf(w2, pd[ic][kx + 1], a11)));
                    }
                }
                a00 = fmaxf(a00, 0.f); a01 = fmaxf(a01, 0.f);
                a10 = fmaxf(a10, 0.f); a11 = fmaxf(a11, 0.f);
                return fmaxf(fmaxf(a00, a01), fmaxf(a10, a11));
            };

            #pragma unroll
            for (int ic = 0; ic < 4; ++ic) {
                load4_lds(P[0][ic], S.s_p1 + ic * 240 + 0 * 16 + x0);
                load4_lds(P[1][ic], S.s_p1 + ic * 240 + 1 * 16 + x0);
            }
            #pragma unroll
            for (int i = 0; i < 3; ++i) {
                const int s0 = (4 * i) % 6, s1 = (4 * i + 1) % 6, s2 = (4 * i + 2) % 6;
                const int s3 = (4 * i + 3) % 6, s4 = (4 * i + 4) % 6, s5 = (4 * i + 5) % 6;
                #pragma unroll
                for (int ic = 0; ic < 4; ++ic) {
                    load4_lds(P[s2][ic], S.s_p1 + ic * 240 + (4 * i + 2) * 16 + x0);
                    load4_lds(P[s3][ic], S.s_p1 + ic * 240 + (4 * i + 3) * 16 + x0);
                }
                S.s_p2[c * 36 + (2 * i) * 6 + px] = c2out(P[s0], P[s1], P[s2], P[s3]);
                #pragma unroll
                for (int ic = 0; ic < 4; ++ic) {
                    load4_lds(P[s4][ic], S.s_p1 + ic * 240 + (4 * i + 4) * 16 + x0);
                    load4_lds(P[s5][ic], S.s_p1 + ic * 240 + (4 * i + 5) * 16 + x0);
                }
                S.s_p2[c * 36 + (2 * i + 1) * 6 + px] = c2out(P[s2], P[s3], P[s4], P[s5]);
            }
        }
        __syncthreads();

        if (lane < 60) {
            const int o = lane / 12, i0 = lane % 12;
            const float* wrow = fcw + o * 360;
            float acc = 0.f;
            #pragma unroll
            for (int k = 0; k < 30; ++k) {
                const int i = i0 + 12 * k;
                acc = fmaf(wrow[i], S.s_p2[i], acc);
            }
            S.s_red[lane] = acc;
        }
        __syncthreads();

        // publish via agent-scope RELAXED atomics: bypass the non-coherent
        // caches, complete at the coherent point. No release fence needed —
        // the __syncthreads below drains vmcnt (stores complete) before the
        // relaxed fetch_add can issue.
        float* dst = enc_in + ((size_t)b * L_ + ts) * 9;
        if (lane < 5) {
            float acc = fcb[lane];
            #pragma unroll
            for (int k = 0; k < 12; ++k) acc += S.s_red[lane * 12 + k];
            __hip_atomic_store(&dst[4 + lane], acc, __ATOMIC_RELAXED, __HIP_MEMORY_SCOPE_AGENT);
        } else if (lane >= 8 && lane < 12) {
            const int d = lane - 8;
            const float* bbp = bbox + (size_t)b * 124 + (size_t)ts * 4;
            __hip_atomic_store(&dst[d], bbp[4 + d] - bbp[d], __ATOMIC_RELAXED, __HIP_MEMORY_SCOPE_AGENT);
        }
        __syncthreads();   // drains vmcnt -> all 4 sub-images' stores complete
        if (lane == 0)
            __hip_atomic_fetch_add(&ctr[ts], 1u, __ATOMIC_RELAXED, __HIP_MEMORY_SCOPE_AGENT);
        return;
    }

    // ======================= GRU role (blocks 0..63) ========================
    const int bb  = (int)blockIdx.x * 16;   // first batch of this block
    const int w   = tid >> 6;               // wave 0..3
    const int l   = tid & 63;
    const int q   = l >> 4;                 // quad 0..3
    const int col = l & 15;
    auto& G = su.g;

    // ---- zero LDS (7168 B = 448 int4) --------------------------------------
    {
        int4* p = (int4*)&G;
        #pragma unroll
        for (int i = 0; i < 2; ++i) {
            const int idx = tid + 256 * i;
            if (idx < (int)(sizeof(G) / 16)) p[idx] = int4{0, 0, 0, 0};
        }
    }

    // ---- weight B-fragments (register-resident, f16) -----------------------
    const int urow = 16 * w + col;
    auto whh_frag = [&](const float* W, int gate, int kap) -> half8 {
        const float* rp = W + (size_t)(gate * 64 + urow) * 64 + kap * 32 + q * 8;
        half8 f;
        #pragma unroll
        for (int j = 0; j < 8; ++j) f[j] = (half_t)rp[j];
        return f;
    };
    auto wih_frag = [&](const float* W, int gate, int indim) -> half8 {
        half8 f;
        #pragma unroll
        for (int j = 0; j < 8; ++j) {
            const int d = q * 8 + j;
            f[j] = (d < indim) ? (half_t)W[(size_t)(gate * 64 + urow) * indim + d]
                               : (half_t)0.f;
        }
        return f;
    };

    // encoder frags only (decoder frags loaded after the encoder loop to keep
    // peak VGPR under the __launch_bounds__(256,3) cap)
    const half8 eBr0 = whh_frag(ewhh, 0, 0), eBr1 = whh_frag(ewhh, 0, 1);
    const half8 eBz0 = whh_frag(ewhh, 1, 0), eBz1 = whh_frag(ewhh, 1, 1);
    const half8 eBn0 = whh_frag(ewhh, 2, 0), eBn1 = whh_frag(ewhh, 2, 1);
    const half8 eBrx = wih_frag(ewih, 0, 9);
    const half8 eBzx = wih_frag(ewih, 1, 9);
    const half8 eBnx = wih_frag(ewih, 2, 9);

    const float ebr  = ebih[urow]       + ebhh[urow];
    const float ebz  = ebih[64 + urow]  + ebhh[64 + urow];
    const float ebnh = ebhh[128 + urow];
    const float ebni = ebih[128 + urow];

    float hold[4] = {0.f, 0.f, 0.f, 0.f};
    __syncthreads();   // LDS zeros visible

    // =================== encoder: 30 steps, paced by conv ==================
    for (int t = 0; t < L_; ++t) {
        if (tid == 0) {
            // RELAXED poll: no buffer_inv per iteration (R10's killer).
            while (__hip_atomic_load(&ctr[t], __ATOMIC_RELAXED, __HIP_MEMORY_SCOPE_AGENT)
                   < (unsigned)B_)
                __builtin_amdgcn_s_sleep(8);
        }
        __syncthreads();
        if (tid < 144) {   // stage 16 batches x 9 dims for this step
            const int bq = tid / 9, d = tid - 9 * bq;
            const float v = __hip_atomic_load(
                &enc_in[((size_t)(bb + bq) * L_ + t) * 9 + d],
                __ATOMIC_RELAXED, __HIP_MEMORY_SCOPE_AGENT);
            G.xenc[bq][d] = (half_t)v;
        }
        __syncthreads();

        const int p = t & 1;
        const half8 a0 = *(const half8*)&G.hbuf[p][col][q * 8];        // k 0..31
        const half8 a1 = *(const half8*)&G.hbuf[p][col][32 + q * 8];   // k 32..63
        const half8 a2 = *(const half8*)&G.xenc[col][q * 8];           // k 64..95

        f32x4 Cr  = {ebr, ebr, ebr, ebr};
        f32x4 Cz  = {ebz, ebz, ebz, ebz};
        f32x4 Cnh = {ebnh, ebnh, ebnh, ebnh};
        f32x4 Cnx = {ebni, ebni, ebni, ebni};
        Cr  = MFMA16(a0, eBr0, Cr);  Cr  = MFMA16(a1, eBr1, Cr);  Cr = MFMA16(a2, eBrx, Cr);
        Cz  = MFMA16(a0, eBz0, Cz);  Cz  = MFMA16(a1, eBz1, Cz);  Cz = MFMA16(a2, eBzx, Cz);
        Cnh = MFMA16(a0, eBn0, Cnh); Cnh = MFMA16(a1, eBn1, Cnh);
        Cnx = MFMA16(a2, eBnx, Cnx);

        #pragma unroll
        for (int r = 0; r < 4; ++r) {
            const float rr = sigmoid_f(Cr[r]);
            const float zz = sigmoid_f(Cz[r]);
            const float nn = tanh_f(Cnx[r] + rr * Cnh[r]);
            hold[r] = fmaf(zz, hold[r] - nn, nn);
            G.hbuf[p ^ 1][q * 4 + r][urow] = (half_t)hold[r];
        }
        __syncthreads();
    }

    // ---- decoder weights / lin head / x0 (loaded after encoder) ------------
    const half8 dBr0 = whh_frag(dwhh, 0, 0), dBr1 = whh_frag(dwhh, 0, 1);
    const half8 dBz0 = whh_frag(dwhh, 1, 0), dBz1 = whh_frag(dwhh, 1, 1);
    const half8 dBn0 = whh_frag(dwhh, 2, 0), dBn1 = whh_frag(dwhh, 2, 1);
    const half8 dBrx = wih_frag(dwih, 0, 4);
    const half8 dBzx = wih_frag(dwih, 1, 4);
    const half8 dBnx = wih_frag(dwih, 2, 4);

    half8 Bl0, Bl1;
    #pragma unroll
    for (int j = 0; j < 8; ++j) {
        Bl0[j] = (col < 4) ? (half_t)linw[col * 64 +      q * 8 + j] : (half_t)0.f;
        Bl1[j] = (col < 4) ? (half_t)linw[col * 64 + 32 + q * 8 + j] : (half_t)0.f;
    }

    const float dbr  = dbih[urow]       + dbhh[urow];
    const float dbz  = dbih[64 + urow]  + dbhh[64 + urow];
    const float dbnh = dbhh[128 + urow];
    const float dbni = dbih[128 + urow];
    const float lb   = (col < 4) ? linb[col] : 0.f;

    float xold[4], ofs[4], cs[4];
    if (w == 0 && col < 4) {
        #pragma unroll
        for (int r = 0; r < 4; ++r) {
            const float* bbp = bbox + (size_t)(bb + q * 4 + r) * 124;
            xold[r] = bbp[120 + col] - bbp[116 + col];
            ofs[r]  = bbp[120 + col];
            cs[r]   = 0.f;
            G.xdec[q * 4 + r][col] = (half_t)xold[r];
        }
    }
    __syncthreads();   // xdec visible

    // =================== decoder: 20 steps + lin + cumsum ==================
    for (int tt = 0; tt < 20; ++tt) {
        const int p = tt & 1;   // (30+tt)&1 == tt&1
        const half8 a0 = *(const half8*)&G.hbuf[p][col][q * 8];
        const half8 a1 = *(const half8*)&G.hbuf[p][col][32 + q * 8];
        const half8 a2 = *(const half8*)&G.xdec[col][q * 8];

        f32x4 Cr  = {dbr, dbr, dbr, dbr};
        f32x4 Cz  = {dbz, dbz, dbz, dbz};
        f32x4 Cnh = {dbnh, dbnh, dbnh, dbnh};
        f32x4 Cnx = {dbni, dbni, dbni, dbni};
        Cr  = MFMA16(a0, dBr0, Cr);  Cr  = MFMA16(a1, dBr1, Cr);  Cr = MFMA16(a2, dBrx, Cr);
        Cz  = MFMA16(a0, dBz0, Cz);  Cz  = MFMA16(a1, dBz1, Cz);  Cz = MFMA16(a2, dBzx, Cz);
        Cnh = MFMA16(a0, dBn0, Cnh); Cnh = MFMA16(a1, dBn1, Cnh);
        Cnx = MFMA16(a2, dBnx, Cnx);

        #pragma unroll
        for (int r = 0; r < 4; ++r) {
            const float rr = sigmoid_f(Cr[r]);
            const float zz = sigmoid_f(Cz[r]);
            const float nn = tanh_f(Cnx[r] + rr * Cnh[r]);
            hold[r] = fmaf(zz, hold[r] - nn, nn);
            G.hbuf[p ^ 1][q * 4 + r][urow] = (half_t)hold[r];
        }
        __syncthreads();   // (A) h_new visible for lin-head A-frags

        const half8 al0 = *(const half8*)&G.hbuf[p ^ 1][col][q * 8];
        const half8 al1 = *(const half8*)&G.hbuf[p ^ 1][col][32 + q * 8];
        f32x4 X = {0.f, 0.f, 0.f, 0.f};
        X = MFMA16(al0, Bl0, X);
        X = MFMA16(al1, Bl1, X);

        if (w == 0 && col < 4) {
            #pragma unroll
            for (int r = 0; r < 4; ++r) {
                const float xv = X[r] + lb + xold[r];
                xold[r] = xv;
                cs[r] += xv;
                G.xdec[q * 4 + r][col] = (half_t)xv;
                out[(size_t)(bb + q * 4 + r) * 80 + tt * 4 + col] = cs[r] + ofs[r];
            }
        }
        __syncthreads();   // (B) xdec visible for next step's gi
    }
}

// ---------------------------------------------------------------------------
extern "C" void kernel_launch(void* const* d_in, const int* in_sizes, int n_in,
                              void* d_out, int out_size, void* d_ws, size_t ws_size,
                              hipStream_t stream) {
    (void)in_sizes; (void)n_in; (void)out_size; (void)ws_size;
    const float* bbox = (const float*)d_in[0];
    const float* head = (const float*)d_in[1];
    const float* c1w  = (const float*)d_in[2];
    const float* c1b  = (const float*)d_in[3];
    const float* c2w  = (const float*)d_in[4];
    const float* c2b  = (const float*)d_in[5];
    const float* fcw  = (const float*)d_in[6];
    const float* fcb  = (const float*)d_in[7];
    const float* ewih = (const float*)d_in[8];
    const float* ewhh = (const float*)d_in[9];
    const float* ebih = (const float*)d_in[10];
    const float* ebhh = (const float*)d_in[11];
    const float* dwih = (const float*)d_in[12];
    const float* dwhh = (const float*)d_in[13];
    const float* dbih = (const float*)d_in[14];
    const float* dbhh = (const float*)d_in[15];
    const float* linw = (const float*)d_in[16];
    const float* linb = (const float*)d_in[17];
    float* out = (float*)d_out;

    float*    enc_in = (float*)d_ws;                       // 1024*30*9 floats
    unsigned* ctr    = (unsigned*)((char*)d_ws + (size_t)B_ * L_ * 9 * sizeof(float));

    hipMemsetAsync(ctr, 0, 32 * sizeof(unsigned), stream); // graph-capturable

    const int grid = NGRUBLK + (B_ * L_) / 4;              // 64 gru + 7680 conv
    fused_kernel<<<grid, 256, 0, stream>>>(bbox, head, c1w, c1b, c2w, c2b,
                                           fcw, fcb, ewih, ewhh, ebih, ebhh,
                                           dwih, dwhh, dbih, dbhh, linw, linb,
                                           enc_in, ctr, out);
}

// Round 3
// 275.447 us; speedup vs baseline: 4.0263x; 2.5553x over previous
//
#include <hip/hip_runtime.h>
#include <hip/hip_bf16.h>

// ---------------------------------------------------------------------------
// Fused pipeline (R12): conv producer + GRU consumer OVERLAPPED in ONE kernel.
//   R11 post-mortem: 30720 relaxed fetch_adds to ONE cache line (ctr[30])
//   serialize at the agent coherent point (~15ns each = ~455us stall).
//   R12: NO atomics at all. Per-conv-block flag dword; GRU block g at step t
//   depends on exactly 4 conv blocks (t-major ordering): cb = t*256+4g+{0..3}.
//   4 private pollers per GRU block, zero address sharing anywhere.
//   Ordering: conv __syncthreads drains vmcnt (agent-scope enc_in stores
//   complete at coherent point) BEFORE the flag store issues; consumer has
//   control dependency + cache-bypassing agent loads. flags re-zeroed per
//   replay by captured hipMemsetAsync.
// ---------------------------------------------------------------------------

#define B_      1024
#define L_      30
#define H_      64
#define NGRUBLK 64

typedef _Float16 half_t;
typedef __attribute__((ext_vector_type(8))) _Float16 half8;
typedef __attribute__((ext_vector_type(4))) float f32x4;

#define MFMA16(A, B, C) __builtin_amdgcn_mfma_f32_16x16x32_f16(A, B, C, 0, 0, 0)

__device__ __forceinline__ float sigmoid_f(float v) {
    return __builtin_amdgcn_rcpf(1.f + __expf(-v));
}
__device__ __forceinline__ float tanh_f(float v) {
    v = fminf(fmaxf(v, -15.f), 15.f);
    const float e = __expf(2.f * v);
    return (e - 1.f) * __builtin_amdgcn_rcpf(e + 1.f);
}
__device__ __forceinline__ void load4_lds(float* r, const float* p) {
    float2 a = *(const float2*)p;
    float2 b = *(const float2*)(p + 2);
    r[0] = a.x; r[1] = a.y; r[2] = b.x; r[3] = b.y;
}

// LDS union: conv role needs 4x9616B = 38464B; GRU role needs 7168B.
union alignas(16) SharedU {
    struct {
        half_t hbuf[2][16][72];   // [parity][batch][unit], rows padded 64->72
        half_t xenc[16][40];      // current-step x, cols 0..8 live, rest zero
        half_t xdec[16][40];      // decoder x,    cols 0..3 live, rest zero
    } g;
    struct {
        float s_img[32 * 32];
        float s_p1[4 * 15 * 16];  // [c][py][px], width padded to 16
        float s_p2[360];
        float s_red[60];
    } c[4];
};

__global__ __launch_bounds__(256, 3) void fused_kernel(
    const float* __restrict__ bbox,
    const float* __restrict__ head,
    const float* __restrict__ c1w, const float* __restrict__ c1b,
    const float* __restrict__ c2w, const float* __restrict__ c2b,
    const float* __restrict__ fcw, const float* __restrict__ fcb,
    const float* __restrict__ ewih, const float* __restrict__ ewhh,
    const float* __restrict__ ebih, const float* __restrict__ ebhh,
    const float* __restrict__ dwih, const float* __restrict__ dwhh,
    const float* __restrict__ dbih, const float* __restrict__ dbhh,
    const float* __restrict__ linw, const float* __restrict__ linb,
    float* __restrict__ enc_in,     // [1024][30][9] in d_ws
    unsigned*            flags,     // [7680] in d_ws, pre-zeroed via memset
    float* __restrict__ out)        // [1024][20][4]
{
    __shared__ SharedU su;
    const int tid = threadIdx.x;

    if (blockIdx.x >= NGRUBLK) {
        // ===================== conv role (4 images / block) =================
        const int cb   = (int)blockIdx.x - NGRUBLK;   // conv block 0..7679
        const int sub  = tid >> 6;
        const int lane = tid & 63;
        const int img  = (cb << 2) | sub;
        const int ts   = img >> 10;       // timestep-major ordering
        const int b    = img & 1023;
        auto& S = su.c[sub];

        {
            const float4* src = (const float4*)(head + ((size_t)b * 31 + (size_t)ts) * 1024);
            float4* dstv = (float4*)S.s_img;
            #pragma unroll
            for (int i = 0; i < 4; ++i) dstv[lane + 64 * i] = src[lane + 64 * i];
        }
        __syncthreads();

        if (lane < 60) {
            const int c = lane / 15, px = lane % 15;
            const int x0 = 2 * px;
            float wg[9];
            #pragma unroll
            for (int k = 0; k < 9; ++k) wg[k] = c1w[c * 9 + k];
            const float bias = c1b[c];

            auto c1out = [&](const float* ra, const float* rb, const float* rc, const float* rd) -> float {
                float a00 = bias, a01 = bias, a10 = bias, a11 = bias;
                #pragma unroll
                for (int kx = 0; kx < 3; ++kx) {
                    const float w0 = wg[kx], w1 = wg[3 + kx], w2 = wg[6 + kx];
                    a00 = fmaf(w0, ra[kx],     fmaf(w1, rb[kx],     fmaf(w2, rc[kx],     a00)));
                    a01 = fmaf(w0, ra[kx + 1], fmaf(w1, rb[kx + 1], fmaf(w2, rc[kx + 1], a01)));
                    a10 = fmaf(w0, rb[kx],     fmaf(w1, rc[kx],     fmaf(w2, rd[kx],     a10)));
                    a11 = fmaf(w0, rb[kx + 1], fmaf(w1, rc[kx + 1], fmaf(w2, rd[kx + 1], a11)));
                }
                a00 = fmaxf(a00, 0.f); a01 = fmaxf(a01, 0.f);
                a10 = fmaxf(a10, 0.f); a11 = fmaxf(a11, 0.f);
                return fmaxf(fmaxf(a00, a01), fmaxf(a10, a11));
            };

            float r[6][4];
            load4_lds(r[0], S.s_img + 0 * 32 + x0);
            load4_lds(r[1], S.s_img + 1 * 32 + x0);
            #pragma unroll
            for (int i = 0; i < 7; ++i) {
                const int s0 = (4 * i) % 6, s1 = (4 * i + 1) % 6, s2 = (4 * i + 2) % 6;
                const int s3 = (4 * i + 3) % 6, s4 = (4 * i + 4) % 6, s5 = (4 * i + 5) % 6;
                load4_lds(r[s2], S.s_img + (4 * i + 2) * 32 + x0);
                load4_lds(r[s3], S.s_img + (4 * i + 3) * 32 + x0);
                S.s_p1[c * 240 + (2 * i) * 16 + px] = c1out(r[s0], r[s1], r[s2], r[s3]);
                load4_lds(r[s4], S.s_img + (4 * i + 4) * 32 + x0);
                load4_lds(r[s5], S.s_img + (4 * i + 5) * 32 + x0);
                S.s_p1[c * 240 + (2 * i + 1) * 16 + px] = c1out(r[s2], r[s3], r[s4], r[s5]);
            }
            load4_lds(r[0], S.s_img + 30 * 32 + x0);
            load4_lds(r[1], S.s_img + 31 * 32 + x0);
            S.s_p1[c * 240 + 14 * 16 + px] = c1out(r[4], r[5], r[0], r[1]);
        }
        __syncthreads();

        if (lane < 60) {
            const int c = lane / 6, px = lane % 6;
            const int x0 = 2 * px;
            float wg2[4][9];
            #pragma unroll
            for (int ic = 0; ic < 4; ++ic)
                #pragma unroll
                for (int k = 0; k < 9; ++k) wg2[ic][k] = c2w[(c * 4 + ic) * 9 + k];
            const float bias2 = c2b[c];

            float P[6][4][4];
            auto c2out = [&](float (*pa)[4], float (*pb)[4], float (*pc)[4], float (*pd)[4]) -> float {
                float a00 = bias2, a01 = bias2, a10 = bias2, a11 = bias2;
                #pragma unroll
                for (int ic = 0; ic < 4; ++ic) {
                    #pragma unroll
                    for (int kx = 0; kx < 3; ++kx) {
                        const float w0 = wg2[ic][kx], w1 = wg2[ic][3 + kx], w2 = wg2[ic][6 + kx];
                        a00 = fmaf(w0, pa[ic][kx],     fmaf(w1, pb[ic][kx],     fmaf(w2, pc[ic][kx],     a00)));
                        a01 = fmaf(w0, pa[ic][kx + 1], fmaf(w1, pb[ic][kx + 1], fmaf(w2, pc[ic][kx + 1], a01)));
                        a10 = fmaf(w0, pb[ic][kx],     fmaf(w1, pc[ic][kx],     fmaf(w2, pd[ic][kx],     a10)));
                        a11 = fmaf(w0, pb[ic][kx + 1], fmaf(w1, pc[ic][kx + 1], fmaf(w2, pd[ic][kx + 1], a11)));
                    }
                }
                a00 = fmaxf(a00, 0.f); a01 = fmaxf(a01, 0.f);
                a10 = fmaxf(a10, 0.f); a11 = fmaxf(a11, 0.f);
                return fmaxf(fmaxf(a00, a01), fmaxf(a10, a11));
            };

            #pragma unroll
            for (int ic = 0; ic < 4; ++ic) {
                load4_lds(P[0][ic], S.s_p1 + ic * 240 + 0 * 16 + x0);
                load4_lds(P[1][ic], S.s_p1 + ic * 240 + 1 * 16 + x0);
            }
            #pragma unroll
            for (int i = 0; i < 3; ++i) {
                const int s0 = (4 * i) % 6, s1 = (4 * i + 1) % 6, s2 = (4 * i + 2) % 6;
                const int s3 = (4 * i + 3) % 6, s4 = (4 * i + 4) % 6, s5 = (4 * i + 5) % 6;
                #pragma unroll
                for (int ic = 0; ic < 4; ++ic) {
                    load4_lds(P[s2][ic], S.s_p1 + ic * 240 + (4 * i + 2) * 16 + x0);
                    load4_lds(P[s3][ic], S.s_p1 + ic * 240 + (4 * i + 3) * 16 + x0);
                }
                S.s_p2[c * 36 + (2 * i) * 6 + px] = c2out(P[s0], P[s1], P[s2], P[s3]);
                #pragma unroll
                for (int ic = 0; ic < 4; ++ic) {
                    load4_lds(P[s4][ic], S.s_p1 + ic * 240 + (4 * i + 4) * 16 + x0);
                    load4_lds(P[s5][ic], S.s_p1 + ic * 240 + (4 * i + 5) * 16 + x0);
                }
                S.s_p2[c * 36 + (2 * i + 1) * 6 + px] = c2out(P[s2], P[s3], P[s4], P[s5]);
            }
        }
        __syncthreads();

        if (lane < 60) {
            const int o = lane / 12, i0 = lane % 12;
            const float* wrow = fcw + o * 360;
            float acc = 0.f;
            #pragma unroll
            for (int k = 0; k < 30; ++k) {
                const int i = i0 + 12 * k;
                acc = fmaf(wrow[i], S.s_p2[i], acc);
            }
            S.s_red[lane] = acc;
        }
        __syncthreads();

        // publish via agent-scope RELAXED stores (bypass non-coherent caches,
        // complete at the coherent point).
        float* dst = enc_in + ((size_t)b * L_ + ts) * 9;
        if (lane < 5) {
            float acc = fcb[lane];
            #pragma unroll
            for (int k = 0; k < 12; ++k) acc += S.s_red[lane * 12 + k];
            __hip_atomic_store(&dst[4 + lane], acc, __ATOMIC_RELAXED, __HIP_MEMORY_SCOPE_AGENT);
        } else if (lane >= 8 && lane < 12) {
            const int d = lane - 8;
            const float* bbp = bbox + (size_t)b * 124 + (size_t)ts * 4;
            __hip_atomic_store(&dst[d], bbp[4 + d] - bbp[d], __ATOMIC_RELAXED, __HIP_MEMORY_SCOPE_AGENT);
        }
        __syncthreads();   // drains vmcnt -> all 4 sub-images' stores complete
        // one private flag store per block — no shared lines, no atomics
        if (tid == 0)
            __hip_atomic_store(&flags[cb], 1u, __ATOMIC_RELAXED, __HIP_MEMORY_SCOPE_AGENT);
        return;
    }

    // ======================= GRU role (blocks 0..63) ========================
    const int g   = (int)blockIdx.x;        // GRU block id
    const int bb  = g * 16;                 // first batch of this block
    const int w   = tid >> 6;               // wave 0..3
    const int l   = tid & 63;
    const int q   = l >> 4;                 // quad 0..3
    const int col = l & 15;
    auto& G = su.g;

    // ---- zero LDS (7168 B = 448 int4) --------------------------------------
    {
        int4* p = (int4*)&G;
        #pragma unroll
        for (int i = 0; i < 2; ++i) {
            const int idx = tid + 256 * i;
            if (idx < (int)(sizeof(G) / 16)) p[idx] = int4{0, 0, 0, 0};
        }
    }

    // ---- weight B-fragments (register-resident, f16) -----------------------
    const int urow = 16 * w + col;
    auto whh_frag = [&](const float* W, int gate, int kap) -> half8 {
        const float* rp = W + (size_t)(gate * 64 + urow) * 64 + kap * 32 + q * 8;
        half8 f;
        #pragma unroll
        for (int j = 0; j < 8; ++j) f[j] = (half_t)rp[j];
        return f;
    };
    auto wih_frag = [&](const float* W, int gate, int indim) -> half8 {
        half8 f;
        #pragma unroll
        for (int j = 0; j < 8; ++j) {
            const int d = q * 8 + j;
            f[j] = (d < indim) ? (half_t)W[(size_t)(gate * 64 + urow) * indim + d]
                               : (half_t)0.f;
        }
        return f;
    };

    // encoder frags only (decoder frags loaded after the encoder loop to keep
    // peak VGPR under the __launch_bounds__(256,3) cap)
    const half8 eBr0 = whh_frag(ewhh, 0, 0), eBr1 = whh_frag(ewhh, 0, 1);
    const half8 eBz0 = whh_frag(ewhh, 1, 0), eBz1 = whh_frag(ewhh, 1, 1);
    const half8 eBn0 = whh_frag(ewhh, 2, 0), eBn1 = whh_frag(ewhh, 2, 1);
    const half8 eBrx = wih_frag(ewih, 0, 9);
    const half8 eBzx = wih_frag(ewih, 1, 9);
    const half8 eBnx = wih_frag(ewih, 2, 9);

    const float ebr  = ebih[urow]       + ebhh[urow];
    const float ebz  = ebih[64 + urow]  + ebhh[64 + urow];
    const float ebnh = ebhh[128 + urow];
    const float ebni = ebih[128 + urow];

    float hold[4] = {0.f, 0.f, 0.f, 0.f};
    __syncthreads();   // LDS zeros visible

    // =================== encoder: 30 steps, paced by conv ==================
    for (int t = 0; t < L_; ++t) {
        // wait only for the 4 conv blocks that produce batches bb..bb+15 at t
        if (tid < 4) {
            const unsigned fidx = (unsigned)(t * 256 + 4 * g + tid);
            while (__hip_atomic_load(&flags[fidx], __ATOMIC_RELAXED,
                                     __HIP_MEMORY_SCOPE_AGENT) == 0u)
                __builtin_amdgcn_s_sleep(2);
        }
        __syncthreads();
        if (tid < 144) {   // stage 16 batches x 9 dims for this step
            const int bq = tid / 9, d = tid - 9 * bq;
            const float v = __hip_atomic_load(
                &enc_in[((size_t)(bb + bq) * L_ + t) * 9 + d],
                __ATOMIC_RELAXED, __HIP_MEMORY_SCOPE_AGENT);
            G.xenc[bq][d] = (half_t)v;
        }
        __syncthreads();

        const int p = t & 1;
        const half8 a0 = *(const half8*)&G.hbuf[p][col][q * 8];        // k 0..31
        const half8 a1 = *(const half8*)&G.hbuf[p][col][32 + q * 8];   // k 32..63
        const half8 a2 = *(const half8*)&G.xenc[col][q * 8];           // k 64..95

        f32x4 Cr  = {ebr, ebr, ebr, ebr};
        f32x4 Cz  = {ebz, ebz, ebz, ebz};
        f32x4 Cnh = {ebnh, ebnh, ebnh, ebnh};
        f32x4 Cnx = {ebni, ebni, ebni, ebni};
        Cr  = MFMA16(a0, eBr0, Cr);  Cr  = MFMA16(a1, eBr1, Cr);  Cr = MFMA16(a2, eBrx, Cr);
        Cz  = MFMA16(a0, eBz0, Cz);  Cz  = MFMA16(a1, eBz1, Cz);  Cz = MFMA16(a2, eBzx, Cz);
        Cnh = MFMA16(a0, eBn0, Cnh); Cnh = MFMA16(a1, eBn1, Cnh);
        Cnx = MFMA16(a2, eBnx, Cnx);

        #pragma unroll
        for (int r = 0; r < 4; ++r) {
            const float rr = sigmoid_f(Cr[r]);
            const float zz = sigmoid_f(Cz[r]);
            const float nn = tanh_f(Cnx[r] + rr * Cnh[r]);
            hold[r] = fmaf(zz, hold[r] - nn, nn);
            G.hbuf[p ^ 1][q * 4 + r][urow] = (half_t)hold[r];
        }
        __syncthreads();
    }

    // ---- decoder weights / lin head / x0 (loaded after encoder) ------------
    const half8 dBr0 = whh_frag(dwhh, 0, 0), dBr1 = whh_frag(dwhh, 0, 1);
    const half8 dBz0 = whh_frag(dwhh, 1, 0), dBz1 = whh_frag(dwhh, 1, 1);
    const half8 dBn0 = whh_frag(dwhh, 2, 0), dBn1 = whh_frag(dwhh, 2, 1);
    const half8 dBrx = wih_frag(dwih, 0, 4);
    const half8 dBzx = wih_frag(dwih, 1, 4);
    const half8 dBnx = wih_frag(dwih, 2, 4);

    half8 Bl0, Bl1;
    #pragma unroll
    for (int j = 0; j < 8; ++j) {
        Bl0[j] = (col < 4) ? (half_t)linw[col * 64 +      q * 8 + j] : (half_t)0.f;
        Bl1[j] = (col < 4) ? (half_t)linw[col * 64 + 32 + q * 8 + j] : (half_t)0.f;
    }

    const float dbr  = dbih[urow]       + dbhh[urow];
    const float dbz  = dbih[64 + urow]  + dbhh[64 + urow];
    const float dbnh = dbhh[128 + urow];
    const float dbni = dbih[128 + urow];
    const float lb   = (col < 4) ? linb[col] : 0.f;

    float xold[4], ofs[4], cs[4];
    if (w == 0 && col < 4) {
        #pragma unroll
        for (int r = 0; r < 4; ++r) {
            const float* bbp = bbox + (size_t)(bb + q * 4 + r) * 124;
            xold[r] = bbp[120 + col] - bbp[116 + col];
            ofs[r]  = bbp[120 + col];
            cs[r]   = 0.f;
            G.xdec[q * 4 + r][col] = (half_t)xold[r];
        }
    }
    __syncthreads();   // xdec visible

    // =================== decoder: 20 steps + lin + cumsum ==================
    for (int tt = 0; tt < 20; ++tt) {
        const int p = tt & 1;   // (30+tt)&1 == tt&1
        const half8 a0 = *(const half8*)&G.hbuf[p][col][q * 8];
        const half8 a1 = *(const half8*)&G.hbuf[p][col][32 + q * 8];
        const half8 a2 = *(const half8*)&G.xdec[col][q * 8];

        f32x4 Cr  = {dbr, dbr, dbr, dbr};
        f32x4 Cz  = {dbz, dbz, dbz, dbz};
        f32x4 Cnh = {dbnh, dbnh, dbnh, dbnh};
        f32x4 Cnx = {dbni, dbni, dbni, dbni};
        Cr  = MFMA16(a0, dBr0, Cr);  Cr  = MFMA16(a1, dBr1, Cr);  Cr = MFMA16(a2, dBrx, Cr);
        Cz  = MFMA16(a0, dBz0, Cz);  Cz  = MFMA16(a1, dBz1, Cz);  Cz = MFMA16(a2, dBzx, Cz);
        Cnh = MFMA16(a0, dBn0, Cnh); Cnh = MFMA16(a1, dBn1, Cnh);
        Cnx = MFMA16(a2, dBnx, Cnx);

        #pragma unroll
        for (int r = 0; r < 4; ++r) {
            const float rr = sigmoid_f(Cr[r]);
            const float zz = sigmoid_f(Cz[r]);
            const float nn = tanh_f(Cnx[r] + rr * Cnh[r]);
            hold[r] = fmaf(zz, hold[r] - nn, nn);
            G.hbuf[p ^ 1][q * 4 + r][urow] = (half_t)hold[r];
        }
        __syncthreads();   // (A) h_new visible for lin-head A-frags

        const half8 al0 = *(const half8*)&G.hbuf[p ^ 1][col][q * 8];
        const half8 al1 = *(const half8*)&G.hbuf[p ^ 1][col][32 + q * 8];
        f32x4 X = {0.f, 0.f, 0.f, 0.f};
        X = MFMA16(al0, Bl0, X);
        X = MFMA16(al1, Bl1, X);

        if (w == 0 && col < 4) {
            #pragma unroll
            for (int r = 0; r < 4; ++r) {
                const float xv = X[r] + lb + xold[r];
                xold[r] = xv;
                cs[r] += xv;
                G.xdec[q * 4 + r][col] = (half_t)xv;
                out[(size_t)(bb + q * 4 + r) * 80 + tt * 4 + col] = cs[r] + ofs[r];
            }
        }
        __syncthreads();   // (B) xdec visible for next step's gi
    }
}

// ---------------------------------------------------------------------------
extern "C" void kernel_launch(void* const* d_in, const int* in_sizes, int n_in,
                              void* d_out, int out_size, void* d_ws, size_t ws_size,
                              hipStream_t stream) {
    (void)in_sizes; (void)n_in; (void)out_size; (void)ws_size;
    const float* bbox = (const float*)d_in[0];
    const float* head = (const float*)d_in[1];
    const float* c1w  = (const float*)d_in[2];
    const float* c1b  = (const float*)d_in[3];
    const float* c2w  = (const float*)d_in[4];
    const float* c2b  = (const float*)d_in[5];
    const float* fcw  = (const float*)d_in[6];
    const float* fcb  = (const float*)d_in[7];
    const float* ewih = (const float*)d_in[8];
    const float* ewhh = (const float*)d_in[9];
    const float* ebih = (const float*)d_in[10];
    const float* ebhh = (const float*)d_in[11];
    const float* dwih = (const float*)d_in[12];
    const float* dwhh = (const float*)d_in[13];
    const float* dbih = (const float*)d_in[14];
    const float* dbhh = (const float*)d_in[15];
    const float* linw = (const float*)d_in[16];
    const float* linb = (const float*)d_in[17];
    float* out = (float*)d_out;

    float*    enc_in = (float*)d_ws;                       // 1024*30*9 floats
    unsigned* flags  = (unsigned*)((char*)d_ws + (size_t)B_ * L_ * 9 * sizeof(float));

    // zero 7680 per-conv-block flags each replay (captured in the graph)
    hipMemsetAsync(flags, 0, (B_ * L_ / 4) * sizeof(unsigned), stream);

    const int grid = NGRUBLK + (B_ * L_) / 4;              // 64 gru + 7680 conv
    fused_kernel<<<grid, 256, 0, stream>>>(bbox, head, c1w, c1b, c2w, c2b,
                                           fcw, fcb, ewih, ewhh, ebih, ebhh,
                                           dwih, dwhh, dbih, dbhh, linw, linb,
                                           enc_in, flags, out);
}